// Round 1
// baseline (341.135 us; speedup 1.0000x reference)
//
#include <hip/hip_runtime.h>
#include <hip/hip_bf16.h>

// Problem constants
#define BB 64
#define NN 500
#define CC 256
#define HH 64
#define WW 64
#define HWSZ 4096   // H*W
#define NPTS 32000  // B*N

// ---------------------------------------------------------------------------
// K0a: per-point bilinear indices + masked weights
// ---------------------------------------------------------------------------
__global__ __launch_bounds__(256) void k_prep(const float* __restrict__ pts,
                                              int4* __restrict__ idx4,
                                              float4* __restrict__ wt4) {
    int i = blockIdx.x * 256 + threadIdx.x;
    if (i >= NPTS) return;
    float x = (pts[i * 2 + 0] + 1.f) * 0.5f * (float)(WW - 1);
    float y = (pts[i * 2 + 1] + 1.f) * 0.5f * (float)(HH - 1);
    float x0f = floorf(x), y0f = floorf(y);
    float x1f = x0f + 1.f, y1f = y0f + 1.f;
    float wx1 = x - x0f, wx0 = 1.f - wx1;
    float wy1 = y - y0f, wy0 = 1.f - wy1;

    float mx0 = (x0f >= 0.f && x0f <= (float)(WW - 1)) ? 1.f : 0.f;
    float mx1 = (x1f >= 0.f && x1f <= (float)(WW - 1)) ? 1.f : 0.f;
    float my0 = (y0f >= 0.f && y0f <= (float)(HH - 1)) ? 1.f : 0.f;
    float my1 = (y1f >= 0.f && y1f <= (float)(HH - 1)) ? 1.f : 0.f;

    int x0 = (int)fminf(fmaxf(x0f, 0.f), (float)(WW - 1));
    int x1 = (int)fminf(fmaxf(x1f, 0.f), (float)(WW - 1));
    int y0 = (int)fminf(fmaxf(y0f, 0.f), (float)(HH - 1));
    int y1 = (int)fminf(fmaxf(y1f, 0.f), (float)(HH - 1));

    idx4[i] = make_int4(y0 * WW + x0, y0 * WW + x1, y1 * WW + x0, y1 * WW + x1);
    wt4[i]  = make_float4(wx0 * wy0 * mx0 * my0,
                          wx1 * wy0 * mx1 * my0,
                          wx0 * wy1 * mx0 * my1,
                          wx1 * wy1 * mx1 * my1);
}

// ---------------------------------------------------------------------------
// K0b: transpose fc_w [236,2500] -> fcwT [2500,236] for coalesced FC reads
// ---------------------------------------------------------------------------
__global__ __launch_bounds__(256) void k_tr(const float* __restrict__ fcw,
                                            float* __restrict__ fcwT) {
    int i = blockIdx.x * 256 + threadIdx.x;
    if (i >= 236 * 2500) return;
    int o = i / 2500;
    int k = i - o * 2500;
    fcwT[k * 236 + o] = fcw[i];
}

// ---------------------------------------------------------------------------
// K1: gather. One block = (batch, 4-channel group). Channel images staged in
// LDS (coalesced streaming read of s_feat exactly once), then 500 points
// bilinear-gather from LDS. feat layout: [B][N][C] (c contiguous).
// ---------------------------------------------------------------------------
#define CHPB 4
__global__ __launch_bounds__(256) void k_gather(const float* __restrict__ sfeat,
                                                const int4* __restrict__ idx4,
                                                const float4* __restrict__ wt4,
                                                float* __restrict__ feat) {
    __shared__ float im[CHPB * HWSZ]; // 64 KB
    const int blk = blockIdx.x;       // 0..B*64
    const int b = blk >> 6;
    const int c0 = (blk & 63) * CHPB;

    const float4* src4 = (const float4*)(sfeat + ((size_t)b * CC + c0) * HWSZ);
    float4* im4 = (float4*)im;
    for (int j = threadIdx.x; j < CHPB * (HWSZ / 4); j += 256) im4[j] = src4[j];
    __syncthreads();

    for (int n = threadIdx.x; n < NN; n += 256) {
        int4 id = idx4[b * NN + n];
        float4 w = wt4[b * NN + n];
        float r[CHPB];
#pragma unroll
        for (int j = 0; j < CHPB; j++) {
            const float* L = im + j * HWSZ;
            r[j] = w.x * L[id.x] + w.y * L[id.y] + w.z * L[id.z] + w.w * L[id.w];
        }
        *(float4*)(feat + ((size_t)(b * NN + n)) * CC + c0) =
            make_float4(r[0], r[1], r[2], r[3]);
    }
}

// ---------------------------------------------------------------------------
// K2: fused 3-layer MLP. Block = (64-point tile, batch), 512 threads = 8 waves.
// Wave g computes an output slice; weights fetched via wave-uniform scalar
// loads (readfirstlane on g). feat/y0/y1 staged in LDS, odd row strides so
// lane-major reads are bank-conflict-free. All f32.
// ---------------------------------------------------------------------------
__global__ __launch_bounds__(512) void k_mlp(const float* __restrict__ feat,
                                             const float* __restrict__ w0,
                                             const float* __restrict__ b0,
                                             const float* __restrict__ w1,
                                             const float* __restrict__ b1,
                                             const float* __restrict__ w2,
                                             const float* __restrict__ b2,
                                             float* __restrict__ y2f) {
    __shared__ float ft[64][257];   // 65792 B
    __shared__ float y0s[64][129];  // 33024 B
    __shared__ float y1s[64][65];   // 16640 B

    const int b   = blockIdx.y;
    const int n0  = blockIdx.x * 64;
    const int tid = threadIdx.x;
    const int p   = tid & 63;
    const int g   = __builtin_amdgcn_readfirstlane(tid >> 6); // wave id, uniform

    // stage feat tile [64][256]
    for (int e4 = tid; e4 < 64 * 64; e4 += 512) {
        int pp = e4 >> 6, c4 = e4 & 63;
        int n = n0 + pp;
        float4 v = make_float4(0.f, 0.f, 0.f, 0.f);
        if (n < NN) v = *(const float4*)(feat + ((size_t)(b * NN + n)) * CC + c4 * 4);
        ft[pp][c4 * 4 + 0] = v.x;
        ft[pp][c4 * 4 + 1] = v.y;
        ft[pp][c4 * 4 + 2] = v.z;
        ft[pp][c4 * 4 + 3] = v.w;
    }
    __syncthreads();

    // ---- layer 0: 128 outputs = 8 waves x 16, K = 256 ----
    {
        const float* wg = w0 + g * 16 * 256;
        float acc[16];
#pragma unroll
        for (int i = 0; i < 16; i++) acc[i] = b0[g * 16 + i];
        for (int kc = 0; kc < 256; kc += 8) {
            float f[8];
#pragma unroll
            for (int kk = 0; kk < 8; kk++) f[kk] = ft[p][kc + kk];
#pragma unroll
            for (int i = 0; i < 16; i++)
#pragma unroll
                for (int kk = 0; kk < 8; kk++)
                    acc[i] = fmaf(wg[i * 256 + kc + kk], f[kk], acc[i]);
        }
#pragma unroll
        for (int i = 0; i < 16; i++) {
            float v = acc[i];
            y0s[p][g * 16 + i] = (v > 0.f) ? v : 0.01f * v;
        }
    }
    __syncthreads();

    // ---- layer 1: 64 outputs = 8 waves x 8, K = 128 (y0) + 256 (feat) ----
    {
        const float* wg = w1 + g * 8 * 384;
        float acc[8];
#pragma unroll
        for (int i = 0; i < 8; i++) acc[i] = b1[g * 8 + i];
        for (int kc = 0; kc < 128; kc += 8) {
            float f[8];
#pragma unroll
            for (int kk = 0; kk < 8; kk++) f[kk] = y0s[p][kc + kk];
#pragma unroll
            for (int i = 0; i < 8; i++)
#pragma unroll
                for (int kk = 0; kk < 8; kk++)
                    acc[i] = fmaf(wg[i * 384 + kc + kk], f[kk], acc[i]);
        }
        for (int kc = 0; kc < 256; kc += 8) {
            float f[8];
#pragma unroll
            for (int kk = 0; kk < 8; kk++) f[kk] = ft[p][kc + kk];
#pragma unroll
            for (int i = 0; i < 8; i++)
#pragma unroll
                for (int kk = 0; kk < 8; kk++)
                    acc[i] = fmaf(wg[i * 384 + 128 + kc + kk], f[kk], acc[i]);
        }
#pragma unroll
        for (int i = 0; i < 8; i++) {
            float v = acc[i];
            y1s[p][g * 8 + i] = (v > 0.f) ? v : 0.01f * v;
        }
    }
    __syncthreads();

    // ---- layer 2: 5 outputs, wave 0 only, K = 64 (y1) + 256 (feat) ----
    if (g == 0) {
        float acc[5];
#pragma unroll
        for (int o = 0; o < 5; o++) acc[o] = b2[o];
        for (int k = 0; k < 64; k++) {
            float f = y1s[p][k];
#pragma unroll
            for (int o = 0; o < 5; o++) acc[o] = fmaf(w2[o * 320 + k], f, acc[o]);
        }
        for (int k = 0; k < 256; k++) {
            float f = ft[p][k];
#pragma unroll
            for (int o = 0; o < 5; o++) acc[o] = fmaf(w2[o * 320 + 64 + k], f, acc[o]);
        }
        int n = n0 + p;
        if (n < NN) {
#pragma unroll
            for (int o = 0; o < 5; o++) {
                float v = acc[o];
                y2f[(size_t)b * (5 * NN) + o * NN + n] = (v > 0.f) ? v : 0.f;
            }
        }
    }
}

// ---------------------------------------------------------------------------
// K3: FC. Block = batch; y row staged in LDS (broadcast reads), fcwT reads
// coalesced across lanes.
// ---------------------------------------------------------------------------
__global__ __launch_bounds__(256) void k_fc(const float* __restrict__ y2f,
                                            const float* __restrict__ fcwT,
                                            const float* __restrict__ fcb,
                                            float* __restrict__ out) {
    __shared__ float ys[2500];
    const int b = blockIdx.x;
    for (int k = threadIdx.x; k < 2500; k += 256) ys[k] = y2f[(size_t)b * 2500 + k];
    __syncthreads();
    const int o = threadIdx.x;
    if (o < 236) {
        float acc = fcb[o];
        for (int k = 0; k < 2500; k++) acc = fmaf(fcwT[k * 236 + o], ys[k], acc);
        out[b * 236 + o] = acc;
    }
}

// ---------------------------------------------------------------------------
extern "C" void kernel_launch(void* const* d_in, const int* in_sizes, int n_in,
                              void* d_out, int out_size, void* d_ws, size_t ws_size,
                              hipStream_t stream) {
    const float* p   = (const float*)d_in[0];
    const float* sf  = (const float*)d_in[1];
    const float* w0  = (const float*)d_in[2];
    const float* b0  = (const float*)d_in[3];
    const float* w1  = (const float*)d_in[4];
    const float* b1  = (const float*)d_in[5];
    const float* w2  = (const float*)d_in[6];
    const float* b2  = (const float*)d_in[7];
    const float* fcw = (const float*)d_in[8];
    const float* fcb = (const float*)d_in[9];
    float* out = (float*)d_out;

    char* ws = (char*)d_ws;
    // ws layout (bytes):
    //   feat : [B][N][C] f32          @ 0          32,768,000
    //   idx4 : [B*N] int4             @ 32,768,000    512,000
    //   wt4  : [B*N] float4           @ 33,280,000    512,000
    //   y2f  : [B][5*N] f32           @ 33,792,000    640,000
    //   fcwT : [2500][236] f32        @ 34,432,000  2,360,000
    float*  feat = (float*)(ws);
    int4*   idx4 = (int4*)(ws + 32768000);
    float4* wt4  = (float4*)(ws + 33280000);
    float*  y2f  = (float*)(ws + 33792000);
    float*  fcwT = (float*)(ws + 34432000);

    k_prep<<<(NPTS + 255) / 256, 256, 0, stream>>>(p, idx4, wt4);
    k_tr<<<(236 * 2500 + 255) / 256, 256, 0, stream>>>(fcw, fcwT);
    k_gather<<<BB * (CC / CHPB), 256, 0, stream>>>(sf, idx4, wt4, feat);
    k_mlp<<<dim3(8, BB), 512, 0, stream>>>(feat, w0, b0, w1, b1, w2, b2, y2f);
    k_fc<<<BB, 256, 0, stream>>>(y2f, fcwT, fcb, out);
}

// Round 2
// 289.175 us; speedup vs baseline: 1.1797x; 1.1797x over previous
//
#include <hip/hip_runtime.h>
#include <hip/hip_bf16.h>

// Problem constants
#define BB 64
#define NN 500
#define CC 256
#define HH 64
#define WW 64
#define HWSZ 4096    // H*W
#define NPTS 32000   // B*N
#define NPAD 504     // N padded to multiple of 8 (point-tile size)
#define TILES 63     // NPAD/8 point-tiles per batch

// ---------------------------------------------------------------------------
// K0a: per-point bilinear indices + masked weights
// ---------------------------------------------------------------------------
__global__ __launch_bounds__(256) void k_prep(const float* __restrict__ pts,
                                              int4* __restrict__ idx4,
                                              float4* __restrict__ wt4) {
    int i = blockIdx.x * 256 + threadIdx.x;
    if (i >= NPTS) return;
    float x = (pts[i * 2 + 0] + 1.f) * 0.5f * (float)(WW - 1);
    float y = (pts[i * 2 + 1] + 1.f) * 0.5f * (float)(HH - 1);
    float x0f = floorf(x), y0f = floorf(y);
    float x1f = x0f + 1.f, y1f = y0f + 1.f;
    float wx1 = x - x0f, wx0 = 1.f - wx1;
    float wy1 = y - y0f, wy0 = 1.f - wy1;

    float mx0 = (x0f >= 0.f && x0f <= (float)(WW - 1)) ? 1.f : 0.f;
    float mx1 = (x1f >= 0.f && x1f <= (float)(WW - 1)) ? 1.f : 0.f;
    float my0 = (y0f >= 0.f && y0f <= (float)(HH - 1)) ? 1.f : 0.f;
    float my1 = (y1f >= 0.f && y1f <= (float)(HH - 1)) ? 1.f : 0.f;

    int x0 = (int)fminf(fmaxf(x0f, 0.f), (float)(WW - 1));
    int x1 = (int)fminf(fmaxf(x1f, 0.f), (float)(WW - 1));
    int y0 = (int)fminf(fmaxf(y0f, 0.f), (float)(HH - 1));
    int y1 = (int)fminf(fmaxf(y1f, 0.f), (float)(HH - 1));

    idx4[i] = make_int4(y0 * WW + x0, y0 * WW + x1, y1 * WW + x0, y1 * WW + x1);
    wt4[i]  = make_float4(wx0 * wy0 * mx0 * my0,
                          wx1 * wy0 * mx1 * my0,
                          wx0 * wy1 * mx0 * my1,
                          wx1 * wy1 * mx1 * my1);
}

// ---------------------------------------------------------------------------
// K0b: pack/transpose all weight matrices to k-major layouts:
//   w0T [256][128], w1T [384][64], w2T [320][8] (5 used, padded), fcwT [2500][236]
// ---------------------------------------------------------------------------
#define W0T_N 32768
#define W1T_N 24576
#define W2T_N 2560
#define FCT_N 590000
#define PACK_N (W0T_N + W1T_N + W2T_N + FCT_N)

__global__ __launch_bounds__(256) void k_pack(const float* __restrict__ w0,
                                              const float* __restrict__ w1,
                                              const float* __restrict__ w2,
                                              const float* __restrict__ fcw,
                                              float* __restrict__ w0T,
                                              float* __restrict__ w1T,
                                              float* __restrict__ w2T,
                                              float* __restrict__ fcwT) {
    int i = blockIdx.x * 256 + threadIdx.x;
    if (i < W0T_N) {
        int k = i >> 7, o = i & 127;
        w0T[i] = w0[o * 256 + k];
    } else if (i < W0T_N + W1T_N) {
        int d = i - W0T_N;
        int k = d >> 6, o = d & 63;
        w1T[d] = w1[o * 384 + k];
    } else if (i < W0T_N + W1T_N + W2T_N) {
        int d = i - (W0T_N + W1T_N);
        int k = d >> 3, o = d & 7;
        w2T[d] = (o < 5) ? w2[o * 320 + k] : 0.f;
    } else if (i < PACK_N) {
        int d = i - (W0T_N + W1T_N + W2T_N);
        int k = d / 236, o = d - k * 236;
        fcwT[d] = fcw[o * 2500 + k];
    }
}

// ---------------------------------------------------------------------------
// K1: gather. One block = (batch, 4-channel group). Channel images staged in
// LDS (s_feat streamed exactly once, coalesced), 500 points gather from LDS.
// feat layout: [B][C][NPAD] (channel-major -> coalesced stores over n).
// ---------------------------------------------------------------------------
#define CHPB 4
__global__ __launch_bounds__(256) void k_gather(const float* __restrict__ sfeat,
                                                const int4* __restrict__ idx4,
                                                const float4* __restrict__ wt4,
                                                float* __restrict__ feat) {
    __shared__ float im[CHPB * HWSZ]; // 64 KB
    const int blk = blockIdx.x;
    const int b = blk >> 6;
    const int c0 = (blk & 63) * CHPB;

    const float4* src4 = (const float4*)(sfeat + ((size_t)b * CC + c0) * HWSZ);
    float4* im4 = (float4*)im;
    for (int j = threadIdx.x; j < CHPB * (HWSZ / 4); j += 256) im4[j] = src4[j];
    __syncthreads();

    for (int n = threadIdx.x; n < NN; n += 256) {
        int4 id = idx4[b * NN + n];
        float4 w = wt4[b * NN + n];
#pragma unroll
        for (int j = 0; j < CHPB; j++) {
            const float* L = im + j * HWSZ;
            float r = w.x * L[id.x] + w.y * L[id.y] + w.z * L[id.z] + w.w * L[id.w];
            feat[((size_t)(b * CC + c0 + j)) * NPAD + n] = r;
        }
    }
}

// ---------------------------------------------------------------------------
// K2a: layer 0. wave = (batch, 8-point tile); lane -> 2 outputs (128 total).
// Activations are wave-uniform scalar loads (s_load_dwordx8 of 8 points);
// weights are per-lane coalesced float2 loads. acc = 16 VGPRs, no LDS.
// ---------------------------------------------------------------------------
__global__ __launch_bounds__(256) void k_l0(const float* __restrict__ feat,
                                            const float* __restrict__ w0T,
                                            const float* __restrict__ b0,
                                            float* __restrict__ y0) {
    const int wv = blockIdx.x * 4 + __builtin_amdgcn_readfirstlane((int)(threadIdx.x >> 6));
    const int l  = threadIdx.x & 63;
    const int b  = wv / TILES;
    const int t  = wv - b * TILES;
    const int n0 = t * 8;
    const int o  = 2 * l;

    float acc0[8], acc1[8];
    float2 bb = *(const float2*)(b0 + o);
#pragma unroll
    for (int p = 0; p < 8; p++) { acc0[p] = bb.x; acc1[p] = bb.y; }

    const float* fp = feat + ((size_t)b * CC) * NPAD + n0;
    const float* wp = w0T + o;
#pragma unroll 4
    for (int k = 0; k < 256; k++) {
        float2 w = *(const float2*)(wp + k * 128);
        const float* a = fp + (size_t)k * NPAD;   // uniform address -> s_load
#pragma unroll
        for (int p = 0; p < 8; p++) {
            float av = a[p];
            acc0[p] = fmaf(w.x, av, acc0[p]);
            acc1[p] = fmaf(w.y, av, acc1[p]);
        }
    }
    float* yp = y0 + ((size_t)b * 128 + o) * NPAD + n0;
#pragma unroll
    for (int p = 0; p < 8; p++) {
        float v0 = acc0[p], v1 = acc1[p];
        yp[p]        = v0 > 0.f ? v0 : 0.01f * v0;
        yp[NPAD + p] = v1 > 0.f ? v1 : 0.01f * v1;
    }
}

// ---------------------------------------------------------------------------
// K2b: layer 1. wave = (batch, 8-point tile); lane -> 1 output (64 total).
// K = 128 (y0) + 256 (feat), both via uniform scalar activation loads.
// ---------------------------------------------------------------------------
__global__ __launch_bounds__(256) void k_l1(const float* __restrict__ feat,
                                            const float* __restrict__ y0,
                                            const float* __restrict__ w1T,
                                            const float* __restrict__ b1,
                                            float* __restrict__ y1) {
    const int wv = blockIdx.x * 4 + __builtin_amdgcn_readfirstlane((int)(threadIdx.x >> 6));
    const int o  = threadIdx.x & 63;
    const int b  = wv / TILES;
    const int t  = wv - b * TILES;
    const int n0 = t * 8;

    float acc[8];
    float bv = b1[o];
#pragma unroll
    for (int p = 0; p < 8; p++) acc[p] = bv;

    const float* ap0 = y0 + ((size_t)b * 128) * NPAD + n0;
#pragma unroll 4
    for (int k = 0; k < 128; k++) {
        float w = w1T[k * 64 + o];
        const float* a = ap0 + (size_t)k * NPAD;
#pragma unroll
        for (int p = 0; p < 8; p++) acc[p] = fmaf(w, a[p], acc[p]);
    }
    const float* ap1 = feat + ((size_t)b * CC) * NPAD + n0;
#pragma unroll 4
    for (int k = 0; k < 256; k++) {
        float w = w1T[(128 + k) * 64 + o];
        const float* a = ap1 + (size_t)k * NPAD;
#pragma unroll
        for (int p = 0; p < 8; p++) acc[p] = fmaf(w, a[p], acc[p]);
    }
    float* yp = y1 + ((size_t)b * 64 + o) * NPAD + n0;
#pragma unroll
    for (int p = 0; p < 8; p++) { float v = acc[p]; yp[p] = v > 0.f ? v : 0.01f * v; }
}

// ---------------------------------------------------------------------------
// K2c: layer 2 (5 outputs). lane = point; weights via uniform s_load from
// padded w2T rows; activation loads coalesced over n. Writes y2f [B][5*N].
// ---------------------------------------------------------------------------
__global__ __launch_bounds__(256) void k_l2(const float* __restrict__ feat,
                                            const float* __restrict__ y1,
                                            const float* __restrict__ w2T,
                                            const float* __restrict__ b2,
                                            float* __restrict__ y2f) {
    int i = blockIdx.x * 256 + threadIdx.x;
    if (i >= NPTS) return;
    int b = i / NN;
    int n = i - b * NN;

    float acc[5];
#pragma unroll
    for (int oo = 0; oo < 5; oo++) acc[oo] = b2[oo];

    const float* yp = y1 + ((size_t)b * 64) * NPAD + n;
#pragma unroll 4
    for (int k = 0; k < 64; k++) {
        float f = yp[(size_t)k * NPAD];
#pragma unroll
        for (int oo = 0; oo < 5; oo++) acc[oo] = fmaf(w2T[k * 8 + oo], f, acc[oo]);
    }
    const float* fp = feat + ((size_t)b * CC) * NPAD + n;
#pragma unroll 4
    for (int k = 0; k < 256; k++) {
        float f = fp[(size_t)k * NPAD];
#pragma unroll
        for (int oo = 0; oo < 5; oo++) acc[oo] = fmaf(w2T[(64 + k) * 8 + oo], f, acc[oo]);
    }
#pragma unroll
    for (int oo = 0; oo < 5; oo++) {
        float v = acc[oo];
        y2f[(size_t)b * 2500 + oo * NN + n] = v > 0.f ? v : 0.f;
    }
}

// ---------------------------------------------------------------------------
// K3: FC, two-stage for parallelism. FC1: 256 blocks = (kc,b), k-chunk 625.
// ---------------------------------------------------------------------------
__global__ __launch_bounds__(256) void k_fc1(const float* __restrict__ y2f,
                                             const float* __restrict__ fcwT,
                                             float* __restrict__ part) {
    __shared__ float ys[625];
    const int b  = blockIdx.x & 63;
    const int kc = blockIdx.x >> 6;
    const float* yb = y2f + (size_t)b * 2500 + kc * 625;
    for (int j = threadIdx.x; j < 625; j += 256) ys[j] = yb[j];
    __syncthreads();
    const int o = threadIdx.x;
    if (o < 236) {
        float acc = 0.f;
        const float* wp = fcwT + (size_t)(kc * 625) * 236 + o;
#pragma unroll 4
        for (int k = 0; k < 625; k++) acc = fmaf(wp[k * 236], ys[k], acc);
        part[((size_t)kc * 64 + b) * 236 + o] = acc;
    }
}

__global__ __launch_bounds__(256) void k_fc2(const float* __restrict__ part,
                                             const float* __restrict__ fcb,
                                             float* __restrict__ out) {
    const int b = blockIdx.x;
    const int o = threadIdx.x;
    if (o < 236) {
        float acc = fcb[o];
#pragma unroll
        for (int kc = 0; kc < 4; kc++) acc += part[((size_t)kc * 64 + b) * 236 + o];
        out[b * 236 + o] = acc;
    }
}

// ---------------------------------------------------------------------------
extern "C" void kernel_launch(void* const* d_in, const int* in_sizes, int n_in,
                              void* d_out, int out_size, void* d_ws, size_t ws_size,
                              hipStream_t stream) {
    const float* p   = (const float*)d_in[0];
    const float* sf  = (const float*)d_in[1];
    const float* w0  = (const float*)d_in[2];
    const float* b0  = (const float*)d_in[3];
    const float* w1  = (const float*)d_in[4];
    const float* b1  = (const float*)d_in[5];
    const float* w2  = (const float*)d_in[6];
    const float* b2  = (const float*)d_in[7];
    const float* fcw = (const float*)d_in[8];
    const float* fcb = (const float*)d_in[9];
    float* out = (float*)d_out;

    char* ws = (char*)d_ws;
    // ws layout (bytes):
    float* feat = (float*)(ws);                 // [64][256][504] 33,030,144
    float* y0   = (float*)(ws + 33030144);      // [64][128][504] 16,515,072
    float* y1   = (float*)(ws + 49545216);      // [64][ 64][504]  8,257,536
    float* y2f  = (float*)(ws + 57802752);      // [64][2500]        640,000
    int4*  idx4 = (int4*) (ws + 58442752);      //                   512,000
    float4* wt4 = (float4*)(ws + 58954752);     //                   512,000
    float* w0T  = (float*)(ws + 59466752);      // [256][128]        131,072
    float* w1T  = (float*)(ws + 59597824);      // [384][64]          98,304
    float* w2T  = (float*)(ws + 59696128);      // [320][8]           10,240
    float* fcwT = (float*)(ws + 59706368);      // [2500][236]     2,360,000
    float* part = (float*)(ws + 62066368);      // [4][64][236]      241,664
                                                // end: 62,308,032

    k_prep<<<(NPTS + 255) / 256, 256, 0, stream>>>(p, idx4, wt4);
    k_pack<<<(PACK_N + 255) / 256, 256, 0, stream>>>(w0, w1, w2, fcw, w0T, w1T, w2T, fcwT);
    k_gather<<<BB * (CC / CHPB), 256, 0, stream>>>(sf, idx4, wt4, feat);
    k_l0<<<(BB * TILES) / 4, 256, 0, stream>>>(feat, w0T, b0, y0);
    k_l1<<<(BB * TILES) / 4, 256, 0, stream>>>(feat, y0, w1T, b1, y1);
    k_l2<<<(NPTS + 255) / 256, 256, 0, stream>>>(feat, y1, w2T, b2, y2f);
    k_fc1<<<256, 256, 0, stream>>>(y2f, fcwT, part);
    k_fc2<<<BB, 256, 0, stream>>>(part, fcb, out);
}

// Round 3
// 256.197 us; speedup vs baseline: 1.3315x; 1.1287x over previous
//
#include <hip/hip_runtime.h>
#include <hip/hip_bf16.h>

// Problem constants
#define BB 64
#define NN 500
#define CC 256
#define HH 64
#define WW 64
#define HWSZ 4096    // H*W
#define NPTS 32000   // B*N
#define NPAD 504     // N padded to multiple of 8 (point-tile size)
#define TILES 63     // NPAD/8 point-tiles per batch

// ---------------------------------------------------------------------------
// K0a: per-point bilinear indices + masked weights
// ---------------------------------------------------------------------------
__global__ __launch_bounds__(256) void k_prep(const float* __restrict__ pts,
                                              int4* __restrict__ idx4,
                                              float4* __restrict__ wt4) {
    int i = blockIdx.x * 256 + threadIdx.x;
    if (i >= NPTS) return;
    float x = (pts[i * 2 + 0] + 1.f) * 0.5f * (float)(WW - 1);
    float y = (pts[i * 2 + 1] + 1.f) * 0.5f * (float)(HH - 1);
    float x0f = floorf(x), y0f = floorf(y);
    float x1f = x0f + 1.f, y1f = y0f + 1.f;
    float wx1 = x - x0f, wx0 = 1.f - wx1;
    float wy1 = y - y0f, wy0 = 1.f - wy1;

    float mx0 = (x0f >= 0.f && x0f <= (float)(WW - 1)) ? 1.f : 0.f;
    float mx1 = (x1f >= 0.f && x1f <= (float)(WW - 1)) ? 1.f : 0.f;
    float my0 = (y0f >= 0.f && y0f <= (float)(HH - 1)) ? 1.f : 0.f;
    float my1 = (y1f >= 0.f && y1f <= (float)(HH - 1)) ? 1.f : 0.f;

    int x0 = (int)fminf(fmaxf(x0f, 0.f), (float)(WW - 1));
    int x1 = (int)fminf(fmaxf(x1f, 0.f), (float)(WW - 1));
    int y0 = (int)fminf(fmaxf(y0f, 0.f), (float)(HH - 1));
    int y1 = (int)fminf(fmaxf(y1f, 0.f), (float)(HH - 1));

    idx4[i] = make_int4(y0 * WW + x0, y0 * WW + x1, y1 * WW + x0, y1 * WW + x1);
    wt4[i]  = make_float4(wx0 * wy0 * mx0 * my0,
                          wx1 * wy0 * mx1 * my0,
                          wx0 * wy1 * mx0 * my1,
                          wx1 * wy1 * mx1 * my1);
}

// ---------------------------------------------------------------------------
// K0b: pack/transpose all weight matrices to k-major layouts:
//   w0T [256][128], w1T [384][64], w2T [320][8] (5 used, padded), fcwT [2500][236]
// ---------------------------------------------------------------------------
#define W0T_N 32768
#define W1T_N 24576
#define W2T_N 2560
#define FCT_N 590000
#define PACK_N (W0T_N + W1T_N + W2T_N + FCT_N)

__global__ __launch_bounds__(256) void k_pack(const float* __restrict__ w0,
                                              const float* __restrict__ w1,
                                              const float* __restrict__ w2,
                                              const float* __restrict__ fcw,
                                              float* __restrict__ w0T,
                                              float* __restrict__ w1T,
                                              float* __restrict__ w2T,
                                              float* __restrict__ fcwT) {
    int i = blockIdx.x * 256 + threadIdx.x;
    if (i < W0T_N) {
        int k = i >> 7, o = i & 127;
        w0T[i] = w0[o * 256 + k];
    } else if (i < W0T_N + W1T_N) {
        int d = i - W0T_N;
        int k = d >> 6, o = d & 63;
        w1T[d] = w1[o * 384 + k];
    } else if (i < W0T_N + W1T_N + W2T_N) {
        int d = i - (W0T_N + W1T_N);
        int k = d >> 3, o = d & 7;
        w2T[d] = (o < 5) ? w2[o * 320 + k] : 0.f;
    } else if (i < PACK_N) {
        int d = i - (W0T_N + W1T_N + W2T_N);
        int k = d / 236, o = d - k * 236;
        fcwT[d] = fcw[o * 2500 + k];
    }
}

// ---------------------------------------------------------------------------
// K1: gather v2. One block = (batch, 2-channel group), 512 threads, 32 KB LDS
// -> 4 blocks/CU (32 waves/CU). Staging via global_load_lds DMA (16 B, no
// VGPR round trip): 4 issues/thread back-to-back = 32 KB in flight per block.
// feat layout: [B][C][NPAD] (channel-major -> coalesced stores over n).
// ---------------------------------------------------------------------------
#define CHPB 2
__global__ __launch_bounds__(512) void k_gather(const float* __restrict__ sfeat,
                                                const int4* __restrict__ idx4,
                                                const float4* __restrict__ wt4,
                                                float* __restrict__ feat) {
    __shared__ float im[CHPB * HWSZ]; // 32 KB
    const int blk = blockIdx.x;
    const int b = blk >> 7;            // 128 channel-groups per batch
    const int c0 = (blk & 127) * CHPB;
    const int tid = threadIdx.x;

    const float4* src4 = (const float4*)(sfeat + ((size_t)b * CC + c0) * HWSZ);
#pragma unroll
    for (int it = 0; it < CHPB * (HWSZ / 4) / 512; it++) {
        int j = it * 512 + tid;
        __builtin_amdgcn_global_load_lds(
            (const __attribute__((address_space(1))) void*)(src4 + j),
            (__attribute__((address_space(3))) void*)((float4*)im + j),
            16, 0, 0);
    }
    __syncthreads();

    if (tid < NN) {
        int n = tid;
        int4 id = idx4[b * NN + n];
        float4 w = wt4[b * NN + n];
#pragma unroll
        for (int j = 0; j < CHPB; j++) {
            const float* L = im + j * HWSZ;
            float r = w.x * L[id.x] + w.y * L[id.y] + w.z * L[id.z] + w.w * L[id.w];
            feat[((size_t)(b * CC + c0 + j)) * NPAD + n] = r;
        }
    }
}

// ---------------------------------------------------------------------------
// K2a: layer 0. wave = (batch, 8-point tile); lane -> 2 outputs (128 total).
// Activations are wave-uniform loads (broadcast); weights per-lane coalesced
// float2 loads. acc = 16 VGPRs, no LDS.
// ---------------------------------------------------------------------------
__global__ __launch_bounds__(256) void k_l0(const float* __restrict__ feat,
                                            const float* __restrict__ w0T,
                                            const float* __restrict__ b0,
                                            float* __restrict__ y0) {
    const int wv = blockIdx.x * 4 + __builtin_amdgcn_readfirstlane((int)(threadIdx.x >> 6));
    const int l  = threadIdx.x & 63;
    const int b  = wv / TILES;
    const int t  = wv - b * TILES;
    const int n0 = t * 8;
    const int o  = 2 * l;

    float acc0[8], acc1[8];
    float2 bb = *(const float2*)(b0 + o);
#pragma unroll
    for (int p = 0; p < 8; p++) { acc0[p] = bb.x; acc1[p] = bb.y; }

    const float* fp = feat + ((size_t)b * CC) * NPAD + n0;
    const float* wp = w0T + o;
#pragma unroll 4
    for (int k = 0; k < 256; k++) {
        float2 w = *(const float2*)(wp + k * 128);
        const float* a = fp + (size_t)k * NPAD;   // uniform address -> broadcast
#pragma unroll
        for (int p = 0; p < 8; p++) {
            float av = a[p];
            acc0[p] = fmaf(w.x, av, acc0[p]);
            acc1[p] = fmaf(w.y, av, acc1[p]);
        }
    }
    float* yp = y0 + ((size_t)b * 128 + o) * NPAD + n0;
#pragma unroll
    for (int p = 0; p < 8; p++) {
        float v0 = acc0[p], v1 = acc1[p];
        yp[p]        = v0 > 0.f ? v0 : 0.01f * v0;
        yp[NPAD + p] = v1 > 0.f ? v1 : 0.01f * v1;
    }
}

// ---------------------------------------------------------------------------
// K2b: layer 1. wave = (batch, 8-point tile); lane -> 1 output (64 total).
// K = 128 (y0) + 256 (feat), both via uniform activation loads.
// ---------------------------------------------------------------------------
__global__ __launch_bounds__(256) void k_l1(const float* __restrict__ feat,
                                            const float* __restrict__ y0,
                                            const float* __restrict__ w1T,
                                            const float* __restrict__ b1,
                                            float* __restrict__ y1) {
    const int wv = blockIdx.x * 4 + __builtin_amdgcn_readfirstlane((int)(threadIdx.x >> 6));
    const int o  = threadIdx.x & 63;
    const int b  = wv / TILES;
    const int t  = wv - b * TILES;
    const int n0 = t * 8;

    float acc[8];
    float bv = b1[o];
#pragma unroll
    for (int p = 0; p < 8; p++) acc[p] = bv;

    const float* ap0 = y0 + ((size_t)b * 128) * NPAD + n0;
#pragma unroll 4
    for (int k = 0; k < 128; k++) {
        float w = w1T[k * 64 + o];
        const float* a = ap0 + (size_t)k * NPAD;
#pragma unroll
        for (int p = 0; p < 8; p++) acc[p] = fmaf(w, a[p], acc[p]);
    }
    const float* ap1 = feat + ((size_t)b * CC) * NPAD + n0;
#pragma unroll 4
    for (int k = 0; k < 256; k++) {
        float w = w1T[(128 + k) * 64 + o];
        const float* a = ap1 + (size_t)k * NPAD;
#pragma unroll
        for (int p = 0; p < 8; p++) acc[p] = fmaf(w, a[p], acc[p]);
    }
    float* yp = y1 + ((size_t)b * 64 + o) * NPAD + n0;
#pragma unroll
    for (int p = 0; p < 8; p++) { float v = acc[p]; yp[p] = v > 0.f ? v : 0.01f * v; }
}

// ---------------------------------------------------------------------------
// K2c: layer 2 (5 outputs). lane = point; weights via uniform loads from
// padded w2T rows; activation loads coalesced over n. Writes y2f [B][5*N].
// ---------------------------------------------------------------------------
__global__ __launch_bounds__(256) void k_l2(const float* __restrict__ feat,
                                            const float* __restrict__ y1,
                                            const float* __restrict__ w2T,
                                            const float* __restrict__ b2,
                                            float* __restrict__ y2f) {
    int i = blockIdx.x * 256 + threadIdx.x;
    if (i >= NPTS) return;
    int b = i / NN;
    int n = i - b * NN;

    float acc[5];
#pragma unroll
    for (int oo = 0; oo < 5; oo++) acc[oo] = b2[oo];

    const float* yp = y1 + ((size_t)b * 64) * NPAD + n;
#pragma unroll 4
    for (int k = 0; k < 64; k++) {
        float f = yp[(size_t)k * NPAD];
#pragma unroll
        for (int oo = 0; oo < 5; oo++) acc[oo] = fmaf(w2T[k * 8 + oo], f, acc[oo]);
    }
    const float* fp = feat + ((size_t)b * CC) * NPAD + n;
#pragma unroll 4
    for (int k = 0; k < 256; k++) {
        float f = fp[(size_t)k * NPAD];
#pragma unroll
        for (int oo = 0; oo < 5; oo++) acc[oo] = fmaf(w2T[(64 + k) * 8 + oo], f, acc[oo]);
    }
#pragma unroll
    for (int oo = 0; oo < 5; oo++) {
        float v = acc[oo];
        y2f[(size_t)b * 2500 + oo * NN + n] = v > 0.f ? v : 0.f;
    }
}

// ---------------------------------------------------------------------------
// K3: FC, two-stage for parallelism. FC1: 256 blocks = (kc,b), k-chunk 625.
// ---------------------------------------------------------------------------
__global__ __launch_bounds__(256) void k_fc1(const float* __restrict__ y2f,
                                             const float* __restrict__ fcwT,
                                             float* __restrict__ part) {
    __shared__ float ys[625];
    const int b  = blockIdx.x & 63;
    const int kc = blockIdx.x >> 6;
    const float* yb = y2f + (size_t)b * 2500 + kc * 625;
    for (int j = threadIdx.x; j < 625; j += 256) ys[j] = yb[j];
    __syncthreads();
    const int o = threadIdx.x;
    if (o < 236) {
        float acc = 0.f;
        const float* wp = fcwT + (size_t)(kc * 625) * 236 + o;
#pragma unroll 4
        for (int k = 0; k < 625; k++) acc = fmaf(wp[k * 236], ys[k], acc);
        part[((size_t)kc * 64 + b) * 236 + o] = acc;
    }
}

__global__ __launch_bounds__(256) void k_fc2(const float* __restrict__ part,
                                             const float* __restrict__ fcb,
                                             float* __restrict__ out) {
    const int b = blockIdx.x;
    const int o = threadIdx.x;
    if (o < 236) {
        float acc = fcb[o];
#pragma unroll
        for (int kc = 0; kc < 4; kc++) acc += part[((size_t)kc * 64 + b) * 236 + o];
        out[b * 236 + o] = acc;
    }
}

// ---------------------------------------------------------------------------
extern "C" void kernel_launch(void* const* d_in, const int* in_sizes, int n_in,
                              void* d_out, int out_size, void* d_ws, size_t ws_size,
                              hipStream_t stream) {
    const float* p   = (const float*)d_in[0];
    const float* sf  = (const float*)d_in[1];
    const float* w0  = (const float*)d_in[2];
    const float* b0  = (const float*)d_in[3];
    const float* w1  = (const float*)d_in[4];
    const float* b1  = (const float*)d_in[5];
    const float* w2  = (const float*)d_in[6];
    const float* b2  = (const float*)d_in[7];
    const float* fcw = (const float*)d_in[8];
    const float* fcb = (const float*)d_in[9];
    float* out = (float*)d_out;

    char* ws = (char*)d_ws;
    // ws layout (bytes):
    float* feat = (float*)(ws);                 // [64][256][504] 33,030,144
    float* y0   = (float*)(ws + 33030144);      // [64][128][504] 16,515,072
    float* y1   = (float*)(ws + 49545216);      // [64][ 64][504]  8,257,536
    float* y2f  = (float*)(ws + 57802752);      // [64][2500]        640,000
    int4*  idx4 = (int4*) (ws + 58442752);      //                   512,000
    float4* wt4 = (float4*)(ws + 58954752);     //                   512,000
    float* w0T  = (float*)(ws + 59466752);      // [256][128]        131,072
    float* w1T  = (float*)(ws + 59597824);      // [384][64]          98,304
    float* w2T  = (float*)(ws + 59696128);      // [320][8]           10,240
    float* fcwT = (float*)(ws + 59706368);      // [2500][236]     2,360,000
    float* part = (float*)(ws + 62066368);      // [4][64][236]      241,664
                                                // end: 62,308,032

    k_prep<<<(NPTS + 255) / 256, 256, 0, stream>>>(p, idx4, wt4);
    k_pack<<<(PACK_N + 255) / 256, 256, 0, stream>>>(w0, w1, w2, fcw, w0T, w1T, w2T, fcwT);
    k_gather<<<BB * (CC / CHPB), 512, 0, stream>>>(sf, idx4, wt4, feat);
    k_l0<<<(BB * TILES) / 4, 256, 0, stream>>>(feat, w0T, b0, y0);
    k_l1<<<(BB * TILES) / 4, 256, 0, stream>>>(feat, y0, w1T, b1, y1);
    k_l2<<<(NPTS + 255) / 256, 256, 0, stream>>>(feat, y1, w2T, b2, y2f);
    k_fc1<<<256, 256, 0, stream>>>(y2f, fcwT, part);
    k_fc2<<<BB, 256, 0, stream>>>(part, fcb, out);
}

// Round 4
// 235.486 us; speedup vs baseline: 1.4486x; 1.0880x over previous
//
#include <hip/hip_runtime.h>
#include <hip/hip_bf16.h>

// Problem constants
#define BB 64
#define NN 500
#define CC 256
#define HH 64
#define WW 64
#define HWSZ 4096    // H*W
#define NPTS 32000   // B*N
#define NPAD 512     // N padded (branchless tile reads)
#define TILE 32      // points per fused-MLP block
#define NT 16        // tiles per batch

// ---------------------------------------------------------------------------
// K0a: per-point bilinear indices + masked weights
// ---------------------------------------------------------------------------
__global__ __launch_bounds__(256) void k_prep(const float* __restrict__ pts,
                                              int4* __restrict__ idx4,
                                              float4* __restrict__ wt4) {
    int i = blockIdx.x * 256 + threadIdx.x;
    if (i >= NPTS) return;
    float x = (pts[i * 2 + 0] + 1.f) * 0.5f * (float)(WW - 1);
    float y = (pts[i * 2 + 1] + 1.f) * 0.5f * (float)(HH - 1);
    float x0f = floorf(x), y0f = floorf(y);
    float x1f = x0f + 1.f, y1f = y0f + 1.f;
    float wx1 = x - x0f, wx0 = 1.f - wx1;
    float wy1 = y - y0f, wy0 = 1.f - wy1;

    float mx0 = (x0f >= 0.f && x0f <= (float)(WW - 1)) ? 1.f : 0.f;
    float mx1 = (x1f >= 0.f && x1f <= (float)(WW - 1)) ? 1.f : 0.f;
    float my0 = (y0f >= 0.f && y0f <= (float)(HH - 1)) ? 1.f : 0.f;
    float my1 = (y1f >= 0.f && y1f <= (float)(HH - 1)) ? 1.f : 0.f;

    int x0 = (int)fminf(fmaxf(x0f, 0.f), (float)(WW - 1));
    int x1 = (int)fminf(fmaxf(x1f, 0.f), (float)(WW - 1));
    int y0 = (int)fminf(fmaxf(y0f, 0.f), (float)(HH - 1));
    int y1 = (int)fminf(fmaxf(y1f, 0.f), (float)(HH - 1));

    idx4[i] = make_int4(y0 * WW + x0, y0 * WW + x1, y1 * WW + x0, y1 * WW + x1);
    wt4[i]  = make_float4(wx0 * wy0 * mx0 * my0,
                          wx1 * wy0 * mx1 * my0,
                          wx0 * wy1 * mx0 * my1,
                          wx1 * wy1 * mx1 * my1);
}

// ---------------------------------------------------------------------------
// K0b: pack/transpose weights to k-major:
//   w0T [256][128], w1T [384][64], w2T [320][8] (5 used), fcwT [2500][236]
// ---------------------------------------------------------------------------
#define W0T_N 32768
#define W1T_N 24576
#define W2T_N 2560
#define FCT_N 590000
#define PACK_N (W0T_N + W1T_N + W2T_N + FCT_N)

__global__ __launch_bounds__(256) void k_pack(const float* __restrict__ w0,
                                              const float* __restrict__ w1,
                                              const float* __restrict__ w2,
                                              const float* __restrict__ fcw,
                                              float* __restrict__ w0T,
                                              float* __restrict__ w1T,
                                              float* __restrict__ w2T,
                                              float* __restrict__ fcwT) {
    int i = blockIdx.x * 256 + threadIdx.x;
    if (i < W0T_N) {
        int k = i >> 7, o = i & 127;
        w0T[i] = w0[o * 256 + k];
    } else if (i < W0T_N + W1T_N) {
        int d = i - W0T_N;
        int k = d >> 6, o = d & 63;
        w1T[d] = w1[o * 384 + k];
    } else if (i < W0T_N + W1T_N + W2T_N) {
        int d = i - (W0T_N + W1T_N);
        int k = d >> 3, o = d & 7;
        w2T[d] = (o < 5) ? w2[o * 320 + k] : 0.f;
    } else if (i < PACK_N) {
        int d = i - (W0T_N + W1T_N + W2T_N);
        int k = d / 236, o = d - k * 236;
        fcwT[d] = fcw[o * 2500 + k];
    }
}

// ---------------------------------------------------------------------------
// K1: gather (unchanged structure). Block = (batch, 2-channel group), 512 thr,
// 32 KB LDS, global_load_lds DMA staging. feat layout [B][C][NPAD].
// ---------------------------------------------------------------------------
#define CHPB 2
__global__ __launch_bounds__(512) void k_gather(const float* __restrict__ sfeat,
                                                const int4* __restrict__ idx4,
                                                const float4* __restrict__ wt4,
                                                float* __restrict__ feat) {
    __shared__ float im[CHPB * HWSZ]; // 32 KB
    const int blk = blockIdx.x;
    const int b = blk >> 7;
    const int c0 = (blk & 127) * CHPB;
    const int tid = threadIdx.x;

    const float4* src4 = (const float4*)(sfeat + ((size_t)b * CC + c0) * HWSZ);
#pragma unroll
    for (int it = 0; it < CHPB * (HWSZ / 4) / 512; it++) {
        int j = it * 512 + tid;
        __builtin_amdgcn_global_load_lds(
            (const __attribute__((address_space(1))) void*)(src4 + j),
            (__attribute__((address_space(3))) void*)((float4*)im + j),
            16, 0, 0);
    }
    __syncthreads();

    if (tid < NN) {
        int n = tid;
        int4 id = idx4[b * NN + n];
        float4 w = wt4[b * NN + n];
#pragma unroll
        for (int j = 0; j < CHPB; j++) {
            const float* L = im + j * HWSZ;
            float r = w.x * L[id.x] + w.y * L[id.y] + w.z * L[id.z] + w.w * L[id.w];
            feat[((size_t)(b * CC + c0 + j)) * NPAD + n] = r;
        }
    }
}

// ---------------------------------------------------------------------------
// K2: fused 3-layer MLP. Block = (b, 32-pt tile), 512 thr (8 waves),
// 2 blocks/CU. feat tile staged once in LDS (ft[c][p], stride 36);
// y0s/y1s live in LDS ([out][pt], stride 34 -> even, b64 act reads).
// L0: thread = (4 outs, 2 pts); L1: (2 outs, 2 pts); L2: k-split 16x20
// + LDS partial reduce (p2 aliases y0s).
// ---------------------------------------------------------------------------
#define FT_S 36
#define Y0_S 34
#define Y1_S 34
#define LDS_FT 0
#define LDS_Y0 (256 * FT_S)                 // 9216
#define LDS_Y1 (LDS_Y0 + 128 * Y0_S)        // 13568
#define LDS_TOT (LDS_Y1 + 64 * Y1_S)        // 15744 floats = 62976 B

__global__ __launch_bounds__(512, 4) void k_mlp(const float* __restrict__ feat,
                                                const float* __restrict__ w0T,
                                                const float* __restrict__ b0,
                                                const float* __restrict__ w1T,
                                                const float* __restrict__ b1,
                                                const float* __restrict__ w2T,
                                                const float* __restrict__ b2,
                                                float* __restrict__ y2f) {
    __shared__ float lds[LDS_TOT];
    float* ft  = lds + LDS_FT;   // [256][FT_S]
    float* y0s = lds + LDS_Y0;   // [128][Y0_S]
    float* y1s = lds + LDS_Y1;   // [64][Y1_S]
    float* p2  = lds + LDS_Y0;   // alias: [16][32][5] partials (y0s dead in L2)

    const int b   = blockIdx.y;
    const int n0  = blockIdx.x * TILE;
    const int tid = threadIdx.x;

    // ---- stage ft[c][p] ----
    const float* fb = feat + ((size_t)b * CC) * NPAD + n0;
    for (int u = tid; u < 256 * 8; u += 512) {
        int c = u >> 3, j = u & 7;
        float4 v = *(const float4*)(fb + (size_t)c * NPAD + j * 4);
        *(float4*)&ft[c * FT_S + j * 4] = v;
    }
    __syncthreads();

    // ---- layer 0: 128 outs, K=256. thread: o0=(tid&31)*4, pts p0,p0+1 ----
    {
        const int o0 = (tid & 31) * 4;
        const int p0 = (tid >> 5) * 2;
        float4 bb = *(const float4*)(b0 + o0);
        float aA0 = bb.x, aA1 = bb.y, aA2 = bb.z, aA3 = bb.w;
        float aB0 = bb.x, aB1 = bb.y, aB2 = bb.z, aB3 = bb.w;
#pragma unroll 4
        for (int k = 0; k < 256; k++) {
            float2 a = *(const float2*)&ft[k * FT_S + p0];
            float4 w = *(const float4*)(w0T + k * 128 + o0);
            aA0 = fmaf(w.x, a.x, aA0); aB0 = fmaf(w.x, a.y, aB0);
            aA1 = fmaf(w.y, a.x, aA1); aB1 = fmaf(w.y, a.y, aB1);
            aA2 = fmaf(w.z, a.x, aA2); aB2 = fmaf(w.z, a.y, aB2);
            aA3 = fmaf(w.w, a.x, aA3); aB3 = fmaf(w.w, a.y, aB3);
        }
        float vA[4] = {aA0, aA1, aA2, aA3};
        float vB[4] = {aB0, aB1, aB2, aB3};
#pragma unroll
        for (int i = 0; i < 4; i++) {
            float x = vA[i], y = vB[i];
            y0s[(o0 + i) * Y0_S + p0]     = x > 0.f ? x : 0.01f * x;
            y0s[(o0 + i) * Y0_S + p0 + 1] = y > 0.f ? y : 0.01f * y;
        }
    }
    __syncthreads();

    // ---- layer 1: 64 outs, K=128(y0)+256(ft). thread: o0=(tid&31)*2 ----
    {
        const int o0 = (tid & 31) * 2;
        const int p0 = (tid >> 5) * 2;
        float2 bb = *(const float2*)(b1 + o0);
        float a00 = bb.x, a01 = bb.x, a10 = bb.y, a11 = bb.y;
#pragma unroll 4
        for (int k = 0; k < 128; k++) {
            float2 a = *(const float2*)&y0s[k * Y0_S + p0];
            float2 w = *(const float2*)(w1T + k * 64 + o0);
            a00 = fmaf(w.x, a.x, a00); a01 = fmaf(w.x, a.y, a01);
            a10 = fmaf(w.y, a.x, a10); a11 = fmaf(w.y, a.y, a11);
        }
#pragma unroll 4
        for (int k = 0; k < 256; k++) {
            float2 a = *(const float2*)&ft[k * FT_S + p0];
            float2 w = *(const float2*)(w1T + (128 + k) * 64 + o0);
            a00 = fmaf(w.x, a.x, a00); a01 = fmaf(w.x, a.y, a01);
            a10 = fmaf(w.y, a.x, a10); a11 = fmaf(w.y, a.y, a11);
        }
        y1s[o0 * Y1_S + p0]           = a00 > 0.f ? a00 : 0.01f * a00;
        y1s[o0 * Y1_S + p0 + 1]       = a01 > 0.f ? a01 : 0.01f * a01;
        y1s[(o0 + 1) * Y1_S + p0]     = a10 > 0.f ? a10 : 0.01f * a10;
        y1s[(o0 + 1) * Y1_S + p0 + 1] = a11 > 0.f ? a11 : 0.01f * a11;
    }
    __syncthreads();

    // ---- layer 2: 5 outs, K=64(y1)+256(ft), k-split 16 x 20 ----
    {
        const int pt = tid & 31;
        const int ks = tid >> 5;
        const int k0 = ks * 20;
        float c0 = 0.f, c1 = 0.f, c2 = 0.f, c3 = 0.f, c4 = 0.f;
#pragma unroll 4
        for (int kk = 0; kk < 20; kk++) {
            int k = k0 + kk;
            float a = (k < 64) ? y1s[k * Y1_S + pt] : ft[(k - 64) * FT_S + pt];
            float4 wa = *(const float4*)(w2T + k * 8);
            float  wb = w2T[k * 8 + 4];
            c0 = fmaf(wa.x, a, c0);
            c1 = fmaf(wa.y, a, c1);
            c2 = fmaf(wa.z, a, c2);
            c3 = fmaf(wa.w, a, c3);
            c4 = fmaf(wb,   a, c4);
        }
        float* pp = p2 + (ks * 32 + pt) * 5;
        pp[0] = c0; pp[1] = c1; pp[2] = c2; pp[3] = c3; pp[4] = c4;
    }
    __syncthreads();

    if (tid < 160) {
        const int pt = tid / 5;
        const int q  = tid - pt * 5;
        float s = b2[q];
#pragma unroll
        for (int g = 0; g < 16; g++) s += p2[(g * 32 + pt) * 5 + q];
        s = fmaxf(s, 0.f);
        int n = n0 + pt;
        if (n < NN) y2f[(size_t)b * 2500 + q * NN + n] = s;
    }
}

// ---------------------------------------------------------------------------
// K3: FC, two-stage. FC1: 512 blocks = (kc 0..7, b), k-chunks of 313/312.
// ---------------------------------------------------------------------------
__global__ __launch_bounds__(256) void k_fc1(const float* __restrict__ y2f,
                                             const float* __restrict__ fcwT,
                                             float* __restrict__ part) {
    __shared__ float ys[313];
    const int b  = blockIdx.x & 63;
    const int kc = blockIdx.x >> 6;
    const int start = kc * 312 + (kc < 4 ? kc : 4);
    const int len   = (kc < 4) ? 313 : 312;
    const float* yb = y2f + (size_t)b * 2500 + start;
    for (int j = threadIdx.x; j < len; j += 256) ys[j] = yb[j];
    __syncthreads();
    const int o = threadIdx.x;
    if (o < 236) {
        float acc = 0.f;
        const float* wp = fcwT + (size_t)start * 236 + o;
#pragma unroll 8
        for (int k = 0; k < len; k++) acc = fmaf(wp[(size_t)k * 236], ys[k], acc);
        part[((size_t)kc * 64 + b) * 236 + o] = acc;
    }
}

__global__ __launch_bounds__(256) void k_fc2(const float* __restrict__ part,
                                             const float* __restrict__ fcb,
                                             float* __restrict__ out) {
    const int b = blockIdx.x;
    const int o = threadIdx.x;
    if (o < 236) {
        float acc = fcb[o];
#pragma unroll
        for (int kc = 0; kc < 8; kc++) acc += part[((size_t)kc * 64 + b) * 236 + o];
        out[b * 236 + o] = acc;
    }
}

// ---------------------------------------------------------------------------
extern "C" void kernel_launch(void* const* d_in, const int* in_sizes, int n_in,
                              void* d_out, int out_size, void* d_ws, size_t ws_size,
                              hipStream_t stream) {
    const float* p   = (const float*)d_in[0];
    const float* sf  = (const float*)d_in[1];
    const float* w0  = (const float*)d_in[2];
    const float* b0  = (const float*)d_in[3];
    const float* w1  = (const float*)d_in[4];
    const float* b1  = (const float*)d_in[5];
    const float* w2  = (const float*)d_in[6];
    const float* b2  = (const float*)d_in[7];
    const float* fcw = (const float*)d_in[8];
    const float* fcb = (const float*)d_in[9];
    float* out = (float*)d_out;

    char* ws = (char*)d_ws;
    // ws layout (bytes):
    float*  feat = (float*)(ws);                // [64][256][512] 33,554,432
    float*  y2f  = (float*)(ws + 33554432);     // [64][2500]        640,000
    int4*   idx4 = (int4*) (ws + 34194432);     //                   512,000
    float4* wt4  = (float4*)(ws + 34706432);    //                   512,000
    float*  w0T  = (float*)(ws + 35218432);     // [256][128]        131,072
    float*  w1T  = (float*)(ws + 35349504);     // [384][64]          98,304
    float*  w2T  = (float*)(ws + 35447808);     // [320][8]           10,240
    float*  fcwT = (float*)(ws + 35458048);     // [2500][236]     2,360,000
    float*  part = (float*)(ws + 37818048);     // [8][64][236]      483,328
                                                // end: 38,301,376

    k_prep<<<(NPTS + 255) / 256, 256, 0, stream>>>(p, idx4, wt4);
    k_pack<<<(PACK_N + 255) / 256, 256, 0, stream>>>(w0, w1, w2, fcw, w0T, w1T, w2T, fcwT);
    k_gather<<<BB * (CC / CHPB), 512, 0, stream>>>(sf, idx4, wt4, feat);
    k_mlp<<<dim3(NT, BB), 512, 0, stream>>>(feat, w0T, b0, w1T, b1, w2T, b2, y2f);
    k_fc1<<<512, 256, 0, stream>>>(y2f, fcwT, part);
    k_fc2<<<BB, 256, 0, stream>>>(part, fcb, out);
}

// Round 7
// 110.076 us; speedup vs baseline: 3.0991x; 2.1393x over previous
//
#include <hip/hip_runtime.h>
#include <hip/hip_bf16.h>

// Problem constants
#define BB 64
#define NN 500
#define CC 256
#define HH 64
#define WW 64
#define HWSZ 4096
#define NPTS 32000
#define NPAD 512

typedef __attribute__((ext_vector_type(8))) short s8v;
typedef __attribute__((ext_vector_type(4))) float f4v;

// split f32 -> hi bf16 + lo bf16 (RNE), x ~= hi + lo with rel err ~2^-17
__device__ __forceinline__ void bfsplit(float f, unsigned short& h, unsigned short& l) {
    unsigned u = __builtin_bit_cast(unsigned, f);
    unsigned hr = (u + 0x7FFFu + ((u >> 16) & 1u)) >> 16;
    h = (unsigned short)hr;
    float hf = __builtin_bit_cast(float, hr << 16);
    float r = f - hf;
    unsigned v = __builtin_bit_cast(unsigned, r);
    unsigned lr = (v + 0x7FFFu + ((v >> 16) & 1u)) >> 16;
    l = (unsigned short)lr;
}

// ---------------------------------------------------------------------------
// K0a: per-point bilinear indices + masked weights
// ---------------------------------------------------------------------------
__global__ __launch_bounds__(256) void k_prep(const float* __restrict__ pts,
                                              int4* __restrict__ idx4,
                                              float4* __restrict__ wt4) {
    int i = blockIdx.x * 256 + threadIdx.x;
    if (i >= NPTS) return;
    float x = (pts[i * 2 + 0] + 1.f) * 0.5f * (float)(WW - 1);
    float y = (pts[i * 2 + 1] + 1.f) * 0.5f * (float)(HH - 1);
    float x0f = floorf(x), y0f = floorf(y);
    float x1f = x0f + 1.f, y1f = y0f + 1.f;
    float wx1 = x - x0f, wx0 = 1.f - wx1;
    float wy1 = y - y0f, wy0 = 1.f - wy1;
    float mx0 = (x0f >= 0.f && x0f <= (float)(WW - 1)) ? 1.f : 0.f;
    float mx1 = (x1f >= 0.f && x1f <= (float)(WW - 1)) ? 1.f : 0.f;
    float my0 = (y0f >= 0.f && y0f <= (float)(HH - 1)) ? 1.f : 0.f;
    float my1 = (y1f >= 0.f && y1f <= (float)(HH - 1)) ? 1.f : 0.f;
    int x0 = (int)fminf(fmaxf(x0f, 0.f), (float)(WW - 1));
    int x1 = (int)fminf(fmaxf(x1f, 0.f), (float)(WW - 1));
    int y0 = (int)fminf(fmaxf(y0f, 0.f), (float)(HH - 1));
    int y1 = (int)fminf(fmaxf(y1f, 0.f), (float)(HH - 1));
    idx4[i] = make_int4(y0 * WW + x0, y0 * WW + x1, y1 * WW + x0, y1 * WW + x1);
    wt4[i]  = make_float4(wx0 * wy0 * mx0 * my0,
                          wx1 * wy0 * mx1 * my0,
                          wx0 * wy1 * mx0 * my1,
                          wx1 * wy1 * mx1 * my1);
}

// ---------------------------------------------------------------------------
// K0b: pack weights to per-lane MFMA A-fragments, split hi/lo bf16:
//   elem i = ((Mt*NS + s)*64 + lane)*8 + j
//   row = Mt*16 + (lane&15), k = s*32 + (lane>>4)*8 + j   <- the k-labeling
// fcwT [2500][236] f32 transpose for the FC.
// ---------------------------------------------------------------------------
#define W0F_N 32768   // 8 Mt * 8 s * 512
#define W1F_N 24576   // 4 Mt * 12 s * 512
#define W2F_N 5120    // 1 Mt * 10 s * 512
#define FCT_N 590000
#define PACK_N (W0F_N + W1F_N + W2F_N + FCT_N)

__global__ __launch_bounds__(256) void k_pack(const float* __restrict__ w0,
                                              const float* __restrict__ w1,
                                              const float* __restrict__ w2,
                                              const float* __restrict__ fcw,
                                              unsigned short* __restrict__ w0fh,
                                              unsigned short* __restrict__ w0fl,
                                              unsigned short* __restrict__ w1fh,
                                              unsigned short* __restrict__ w1fl,
                                              unsigned short* __restrict__ w2fh,
                                              unsigned short* __restrict__ w2fl,
                                              float* __restrict__ fcwT) {
    int i = blockIdx.x * 256 + threadIdx.x;
    if (i < W0F_N) {
        int j = i & 7, ll = (i >> 3) & 63, s = (i >> 9) & 7, m = i >> 12;
        int row = m * 16 + (ll & 15), k = s * 32 + (ll >> 4) * 8 + j;
        unsigned short h, l; bfsplit(w0[row * 256 + k], h, l);
        w0fh[i] = h; w0fl[i] = l;
    } else if (i < W0F_N + W1F_N) {
        int d = i - W0F_N;
        int j = d & 7, ll = (d >> 3) & 63, rest = d >> 9;
        int s = rest % 12, m = rest / 12;
        int row = m * 16 + (ll & 15), k = s * 32 + (ll >> 4) * 8 + j;
        unsigned short h, l; bfsplit(w1[row * 384 + k], h, l);
        w1fh[d] = h; w1fl[d] = l;
    } else if (i < W0F_N + W1F_N + W2F_N) {
        int d = i - (W0F_N + W1F_N);
        int j = d & 7, ll = (d >> 3) & 63, s = d >> 9;
        int row = ll & 15, k = s * 32 + (ll >> 4) * 8 + j;
        float v = (row < 5) ? w2[row * 320 + k] : 0.f;
        unsigned short h, l; bfsplit(v, h, l);
        w2fh[d] = h; w2fl[d] = l;
    } else if (i < PACK_N) {
        int d = i - (W0F_N + W1F_N + W2F_N);
        int k = d / 236, o = d - k * 236;
        fcwT[d] = fcw[o * 2500 + k];
    }
}

// ---------------------------------------------------------------------------
// K1: gather. Block = (batch, 2-channel group), 512 thr, 32 KB LDS,
// global_load_lds DMA staging. feat layout [B][C][NPAD] f32.
// ---------------------------------------------------------------------------
#define CHPB 2
__global__ __launch_bounds__(512) void k_gather(const float* __restrict__ sfeat,
                                                const int4* __restrict__ idx4,
                                                const float4* __restrict__ wt4,
                                                float* __restrict__ feat) {
    __shared__ float im[CHPB * HWSZ];
    const int blk = blockIdx.x;
    const int b = blk >> 7;
    const int c0 = (blk & 127) * CHPB;
    const int tid = threadIdx.x;

    const float4* src4 = (const float4*)(sfeat + ((size_t)b * CC + c0) * HWSZ);
#pragma unroll
    for (int it = 0; it < CHPB * (HWSZ / 4) / 512; it++) {
        int j = it * 512 + tid;
        __builtin_amdgcn_global_load_lds(
            (const __attribute__((address_space(1))) void*)(src4 + j),
            (__attribute__((address_space(3))) void*)((float4*)im + j),
            16, 0, 0);
    }
    __syncthreads();

    if (tid < NN) {
        int n = tid;
        int4 id = idx4[b * NN + n];
        float4 w = wt4[b * NN + n];
#pragma unroll
        for (int j = 0; j < CHPB; j++) {
            const float* L = im + j * HWSZ;
            float r = w.x * L[id.x] + w.y * L[id.y] + w.z * L[id.z] + w.w * L[id.w];
            feat[((size_t)(b * CC + c0 + j)) * NPAD + n] = r;
        }
    }
}

// ---------------------------------------------------------------------------
// K2: split-bf16 MFMA fused MLP, register-resident B-fragments.
// Block = (batch, 32-pt tile), 512 thr = 8 waves; wave w: nt=w&1, mh=w>>1.
// Lane builds its OWN B-fragments from global feat with k-label
//   k = s*32 + (l>>4)*8 + j  (identical labeling to the A-pack -> provably
//   correct contraction independent of the HW's internal k map).
// C/D mapping (m89-verified): col = lane&15, row = (lane>>4)*4 + reg.
// c1/c2 in LDS col-major [pt][ch] -> contiguous b128 B-frag reads.
// ---------------------------------------------------------------------------
#define K1_S 136
#define K2_S 72

__device__ __forceinline__ s8v mkfrag(const unsigned short* p) {
    return *(const s8v*)p;
}

__global__ __launch_bounds__(512, 4) void k_mlp(const float* __restrict__ feat,
                                                const unsigned short* __restrict__ w0fh,
                                                const unsigned short* __restrict__ w0fl,
                                                const unsigned short* __restrict__ w1fh,
                                                const unsigned short* __restrict__ w1fl,
                                                const unsigned short* __restrict__ w2fh,
                                                const unsigned short* __restrict__ w2fl,
                                                const float* __restrict__ b0,
                                                const float* __restrict__ b1,
                                                const float* __restrict__ b2,
                                                float* __restrict__ y2f) {
    __shared__ unsigned short c1H[32 * K1_S];
    __shared__ unsigned short c1L[32 * K1_S];
    __shared__ unsigned short c2H[32 * K2_S];
    __shared__ unsigned short c2L[32 * K2_S];   // total 26,624 B

    const int b   = blockIdx.y;
    const int n0  = blockIdx.x * 32;
    const int tid = threadIdx.x;
    const int w   = tid >> 6, l = tid & 63;
    const int nt  = w & 1, mh = w >> 1;
    const int lo16 = l & 15, hi = l >> 4;
    const int c = nt * 16 + lo16;          // point column 0..31

    // ---- B-fragments (feat) -> registers, hi/lo split ----
    s8v bhs[8], bls[8];
    const float* fp = feat + ((size_t)b * CC) * NPAD + n0 + c;
#pragma unroll
    for (int s = 0; s < 8; s++) {
        s8v h, lo;
#pragma unroll
        for (int j = 0; j < 8; j++) {
            int k = s * 32 + hi * 8 + j;
            float v = fp[(size_t)k * NPAD];
            unsigned short hh, ll2; bfsplit(v, hh, ll2);
            h[j] = (short)hh; lo[j] = (short)ll2;
        }
        bhs[s] = h; bls[s] = lo;
    }

    // ---- layer 0: 128 outs (8 Mt), K=256; wave does Mt = 2mh, 2mh+1 ----
    f4v acc0 = {0.f, 0.f, 0.f, 0.f}, acc1 = {0.f, 0.f, 0.f, 0.f};
#pragma unroll
    for (int s = 0; s < 8; s++) {
        const s8v a0h = mkfrag(w0fh + ((size_t)((mh * 2) * 8 + s) * 64 + l) * 8);
        const s8v a0l = mkfrag(w0fl + ((size_t)((mh * 2) * 8 + s) * 64 + l) * 8);
        const s8v a1h = mkfrag(w0fh + ((size_t)((mh * 2 + 1) * 8 + s) * 64 + l) * 8);
        const s8v a1l = mkfrag(w0fl + ((size_t)((mh * 2 + 1) * 8 + s) * 64 + l) * 8);
        acc0 = __builtin_amdgcn_mfma_f32_16x16x32_bf16(a0h, bhs[s], acc0, 0, 0, 0);
        acc0 = __builtin_amdgcn_mfma_f32_16x16x32_bf16(a0h, bls[s], acc0, 0, 0, 0);
        acc0 = __builtin_amdgcn_mfma_f32_16x16x32_bf16(a0l, bhs[s], acc0, 0, 0, 0);
        acc1 = __builtin_amdgcn_mfma_f32_16x16x32_bf16(a1h, bhs[s], acc1, 0, 0, 0);
        acc1 = __builtin_amdgcn_mfma_f32_16x16x32_bf16(a1h, bls[s], acc1, 0, 0, 0);
        acc1 = __builtin_amdgcn_mfma_f32_16x16x32_bf16(a1l, bhs[s], acc1, 0, 0, 0);
    }
#pragma unroll
    for (int m = 0; m < 2; m++) {
#pragma unroll
        for (int r = 0; r < 4; r++) {
            int ch = (mh * 2 + m) * 16 + hi * 4 + r;
            float v = (m ? acc1[r] : acc0[r]) + b0[ch];
            v = v > 0.f ? v : 0.01f * v;
            unsigned short hh, ll2; bfsplit(v, hh, ll2);
            c1H[c * K1_S + ch] = hh;
            c1L[c * K1_S + ch] = ll2;
        }
    }
    __syncthreads();

    // ---- layer 1: 64 outs (4 Mt), K=128(c1)+256(feat); wave: Mt = mh ----
    f4v accA = {0.f, 0.f, 0.f, 0.f};
#pragma unroll
    for (int s = 0; s < 4; s++) {
        const s8v bh = *(const s8v*)&c1H[c * K1_S + s * 32 + hi * 8];
        const s8v bl = *(const s8v*)&c1L[c * K1_S + s * 32 + hi * 8];
        const s8v ah = mkfrag(w1fh + ((size_t)(mh * 12 + s) * 64 + l) * 8);
        const s8v al = mkfrag(w1fl + ((size_t)(mh * 12 + s) * 64 + l) * 8);
        accA = __builtin_amdgcn_mfma_f32_16x16x32_bf16(ah, bh, accA, 0, 0, 0);
        accA = __builtin_amdgcn_mfma_f32_16x16x32_bf16(ah, bl, accA, 0, 0, 0);
        accA = __builtin_amdgcn_mfma_f32_16x16x32_bf16(al, bh, accA, 0, 0, 0);
    }
#pragma unroll
    for (int s = 4; s < 12; s++) {
        const s8v ah = mkfrag(w1fh + ((size_t)(mh * 12 + s) * 64 + l) * 8);
        const s8v al = mkfrag(w1fl + ((size_t)(mh * 12 + s) * 64 + l) * 8);
        accA = __builtin_amdgcn_mfma_f32_16x16x32_bf16(ah, bhs[s - 4], accA, 0, 0, 0);
        accA = __builtin_amdgcn_mfma_f32_16x16x32_bf16(ah, bls[s - 4], accA, 0, 0, 0);
        accA = __builtin_amdgcn_mfma_f32_16x16x32_bf16(al, bhs[s - 4], accA, 0, 0, 0);
    }
#pragma unroll
    for (int r = 0; r < 4; r++) {
        int ch = mh * 16 + hi * 4 + r;
        float v = accA[r] + b1[ch];
        v = v > 0.f ? v : 0.01f * v;
        unsigned short hh, ll2; bfsplit(v, hh, ll2);
        c2H[c * K2_S + ch] = hh;
        c2L[c * K2_S + ch] = ll2;
    }
    __syncthreads();

    // ---- layer 2: 5 outs (1 Mt), K=64(c2)+256(feat); waves mh==0 ----
    if (mh == 0) {
        f4v acc2 = {0.f, 0.f, 0.f, 0.f};
#pragma unroll
        for (int s = 0; s < 2; s++) {
            const s8v bh = *(const s8v*)&c2H[c * K2_S + s * 32 + hi * 8];
            const s8v bl = *(const s8v*)&c2L[c * K2_S + s * 32 + hi * 8];
            const s8v ah = mkfrag(w2fh + ((size_t)s * 64 + l) * 8);
            const s8v al = mkfrag(w2fl + ((size_t)s * 64 + l) * 8);
            acc2 = __builtin_amdgcn_mfma_f32_16x16x32_bf16(ah, bh, acc2, 0, 0, 0);
            acc2 = __builtin_amdgcn_mfma_f32_16x16x32_bf16(ah, bl, acc2, 0, 0, 0);
            acc2 = __builtin_amdgcn_mfma_f32_16x16x32_bf16(al, bh, acc2, 0, 0, 0);
        }
#pragma unroll
        for (int s = 2; s < 10; s++) {
            const s8v ah = mkfrag(w2fh + ((size_t)s * 64 + l) * 8);
            const s8v al = mkfrag(w2fl + ((size_t)s * 64 + l) * 8);
            acc2 = __builtin_amdgcn_mfma_f32_16x16x32_bf16(ah, bhs[s - 2], acc2, 0, 0, 0);
            acc2 = __builtin_amdgcn_mfma_f32_16x16x32_bf16(ah, bls[s - 2], acc2, 0, 0, 0);
            acc2 = __builtin_amdgcn_mfma_f32_16x16x32_bf16(al, bhs[s - 2], acc2, 0, 0, 0);
        }
#pragma unroll
        for (int r = 0; r < 4; r++) {
            int ch = hi * 4 + r;
            if (ch < 5) {
                float v = acc2[r] + b2[ch];
                v = fmaxf(v, 0.f);
                int n = n0 + c;
                if (n < NN) y2f[(size_t)b * 2500 + ch * NN + n] = v;
            }
        }
    }
}

// ---------------------------------------------------------------------------
// K3: FC, two-stage. FC1: 512 blocks = (kc 0..7, b), k-chunks of 313/312.
// ---------------------------------------------------------------------------
__global__ __launch_bounds__(256) void k_fc1(const float* __restrict__ y2f,
                                             const float* __restrict__ fcwT,
                                             float* __restrict__ part) {
    __shared__ float ys[313];
    const int b  = blockIdx.x & 63;
    const int kc = blockIdx.x >> 6;
    const int start = kc * 312 + (kc < 4 ? kc : 4);
    const int len   = (kc < 4) ? 313 : 312;
    const float* yb = y2f + (size_t)b * 2500 + start;
    for (int j = threadIdx.x; j < len; j += 256) ys[j] = yb[j];
    __syncthreads();
    const int o = threadIdx.x;
    if (o < 236) {
        float acc = 0.f;
        const float* wp = fcwT + (size_t)start * 236 + o;
#pragma unroll 8
        for (int k = 0; k < len; k++) acc = fmaf(wp[(size_t)k * 236], ys[k], acc);
        part[((size_t)kc * 64 + b) * 236 + o] = acc;
    }
}

__global__ __launch_bounds__(256) void k_fc2(const float* __restrict__ part,
                                             const float* __restrict__ fcb,
                                             float* __restrict__ out) {
    const int b = blockIdx.x;
    const int o = threadIdx.x;
    if (o < 236) {
        float acc = fcb[o];
#pragma unroll
        for (int kc = 0; kc < 8; kc++) acc += part[((size_t)kc * 64 + b) * 236 + o];
        out[b * 236 + o] = acc;
    }
}

// ---------------------------------------------------------------------------
extern "C" void kernel_launch(void* const* d_in, const int* in_sizes, int n_in,
                              void* d_out, int out_size, void* d_ws, size_t ws_size,
                              hipStream_t stream) {
    const float* p   = (const float*)d_in[0];
    const float* sf  = (const float*)d_in[1];
    const float* w0  = (const float*)d_in[2];
    const float* b0  = (const float*)d_in[3];
    const float* w1  = (const float*)d_in[4];
    const float* b1  = (const float*)d_in[5];
    const float* w2  = (const float*)d_in[6];
    const float* b2  = (const float*)d_in[7];
    const float* fcw = (const float*)d_in[8];
    const float* fcb = (const float*)d_in[9];
    float* out = (float*)d_out;

    char* ws = (char*)d_ws;
    float*  feat = (float*)(ws);                       // 33,554,432
    float*  y2f  = (float*)(ws + 33554432);            //    640,000
    int4*   idx4 = (int4*) (ws + 34194432);            //    512,000
    float4* wt4  = (float4*)(ws + 34706432);           //    512,000
    float*  fcwT = (float*)(ws + 35218432);            //  2,360,000
    float*  part = (float*)(ws + 37578432);            //    483,328
    unsigned short* w0fh = (unsigned short*)(ws + 38061760); // 65,536
    unsigned short* w0fl = (unsigned short*)(ws + 38127296); // 65,536
    unsigned short* w1fh = (unsigned short*)(ws + 38192832); // 49,152
    unsigned short* w1fl = (unsigned short*)(ws + 38241984); // 49,152
    unsigned short* w2fh = (unsigned short*)(ws + 38291136); // 10,240
    unsigned short* w2fl = (unsigned short*)(ws + 38301376); // 10,240

    k_prep<<<(NPTS + 255) / 256, 256, 0, stream>>>(p, idx4, wt4);
    k_pack<<<(PACK_N + 255) / 256, 256, 0, stream>>>(w0, w1, w2, fcw,
                                                     w0fh, w0fl, w1fh, w1fl,
                                                     w2fh, w2fl, fcwT);
    k_gather<<<BB * (CC / CHPB), 512, 0, stream>>>(sf, idx4, wt4, feat);
    k_mlp<<<dim3(16, BB), 512, 0, stream>>>(feat, w0fh, w0fl, w1fh, w1fl,
                                            w2fh, w2fl, b0, b1, b2, y2f);
    k_fc1<<<512, 256, 0, stream>>>(y2f, fcwT, part);
    k_fc2<<<BB, 256, 0, stream>>>(part, fcb, out);
}